// Round 1
// baseline (281.263 us; speedup 1.0000x reference)
//
#include <hip/hip_runtime.h>

// Fused MHA: x(4,1024,1024) fp32, mask(4,1024) i32, w_qkv(3072,1024), b_qkv,
// w_out(1024,1024), b_out -> out(4,1024,1024) fp32.
// Pipeline: prep-cast -> mask-sum -> qkv GEMM (bf16 MFMA) -> flash attn -> out GEMM.

#define NHEADS 16
#define DHEAD  64
#define EDIM   1024
#define SLEN   1024
#define BATCH  4

typedef short bf16x8 __attribute__((ext_vector_type(8)));
typedef float f32x4  __attribute__((ext_vector_type(4)));

#define MFMA_BF16(a,b,c) __builtin_amdgcn_mfma_f32_16x16x32_bf16((a),(b),(c),0,0,0)

typedef const __attribute__((address_space(1))) void gvoid_t;
typedef __attribute__((address_space(3))) void lvoid_t;

__device__ __forceinline__ unsigned short f2bf(float x) {
  union { float f; unsigned int u; } v; v.f = x;
  unsigned int r = v.u + 0x7fffu + ((v.u >> 16) & 1u);
  return (unsigned short)(r >> 16);
}

__device__ __forceinline__ void gl2lds16(const void* g, void* l) {
  __builtin_amdgcn_global_load_lds((gvoid_t*)g, (lvoid_t*)l, 16, 0, 0);
}

// ---------------- prep: fp32 -> bf16 casts ----------------
__global__ __launch_bounds__(256) void prep_cast(
    const float* __restrict__ x, const float* __restrict__ wq,
    const float* __restrict__ wo,
    unsigned short* __restrict__ xb, unsigned short* __restrict__ wqb,
    unsigned short* __restrict__ wob) {
  int i = blockIdx.x * 256 + threadIdx.x;
  const int NX  = BATCH * SLEN * EDIM / 4;   // 1048576
  const int NW1 = 3 * EDIM * EDIM / 4;       // 786432
  const float4* src; unsigned short* dst; int j;
  if (i < NX)           { src = (const float4*)x;  dst = xb;  j = i; }
  else if (i < NX+NW1)  { src = (const float4*)wq; dst = wqb; j = i - NX; }
  else                  { src = (const float4*)wo; dst = wob; j = i - NX - NW1; }
  float4 v = src[j];
  ushort4 o;
  o.x = f2bf(v.x); o.y = f2bf(v.y); o.z = f2bf(v.z); o.w = f2bf(v.w);
  ((ushort4*)dst)[j] = o;
}

// ---------------- mask row-sum: L[b] ----------------
__global__ __launch_bounds__(256) void mask_sum(const int* __restrict__ mask,
                                                int* __restrict__ L) {
  int b = blockIdx.x;
  int t = threadIdx.x;
  int s = 0;
  for (int i = t; i < SLEN; i += 256) s += mask[b * SLEN + i];
  #pragma unroll
  for (int m = 1; m < 64; m <<= 1) s += __shfl_xor(s, m);
  __shared__ int part[4];
  if ((t & 63) == 0) part[t >> 6] = s;
  __syncthreads();
  if (t == 0) L[b] = part[0] + part[1] + part[2] + part[3];
}

// ---------------- GEMM C = A @ B^T (A:[M][K], B:[N][K], bf16, m97 structure) ----
// EPI=0: qkv epilogue (bias + scatter to q/k row-major, v transposed), bf16 out
// EPI=1: out-proj epilogue (bias), fp32 out
template<int EPI>
__global__ __launch_bounds__(256) void gemm_bt(
    const unsigned short* __restrict__ A, const unsigned short* __restrict__ B,
    int M, int N, int K,
    const float* __restrict__ bias,
    float* __restrict__ outf,
    unsigned short* __restrict__ qb, unsigned short* __restrict__ kb,
    unsigned short* __restrict__ vb) {
  __shared__ __align__(16) unsigned short lds_a[128 * 32];
  __shared__ __align__(16) unsigned short lds_b[128 * 32];
  const int tid = threadIdx.x;
  const int w = tid >> 6, l = tid & 63;
  const int g = l >> 4, ln = l & 15;
  const int ntile = N >> 7;
  const int tm = blockIdx.x / ntile, tn = blockIdx.x % ntile;
  const int mBase = tm << 7, nBase = tn << 7;
  const int wr = w >> 1, wc = w & 1;

  f32x4 zz = {0.f, 0.f, 0.f, 0.f};
  f32x4 acc[4][4];
  #pragma unroll
  for (int m = 0; m < 4; ++m)
    #pragma unroll
    for (int n = 0; n < 4; ++n) acc[m][n] = zz;

  // staging geometry: 128x32 bf16 tile = 8KB = 512 x 16B; 2 insts x 256 thr
  const int u0 = tid, u1 = tid + 256;
  const int r0 = u0 >> 2, c0 = (u0 & 3) << 3;
  const int r1 = u1 >> 2, c1 = (u1 & 3) << 3;
  const unsigned short* Ab = A + mBase * K;
  const unsigned short* Bb = B + nBase * K;
  unsigned short* da0 = &lds_a[(w * 64) * 8];          // + lane*16B by HW
  unsigned short* da1 = &lds_a[(256 + w * 64) * 8];
  unsigned short* db0 = &lds_b[(w * 64) * 8];
  unsigned short* db1 = &lds_b[(256 + w * 64) * 8];

  for (int k0 = 0; k0 < K; k0 += 32) {
    gl2lds16(Ab + r0 * K + k0 + c0, da0);
    gl2lds16(Ab + r1 * K + k0 + c1, da1);
    gl2lds16(Bb + r0 * K + k0 + c0, db0);
    gl2lds16(Bb + r1 * K + k0 + c1, db1);
    __syncthreads();
    bf16x8 af[4], bfr[4];
    #pragma unroll
    for (int m = 0; m < 4; ++m)
      af[m] = *(const bf16x8*)&lds_a[(wr * 64 + m * 16 + ln) * 32 + g * 8];
    #pragma unroll
    for (int n = 0; n < 4; ++n)
      bfr[n] = *(const bf16x8*)&lds_b[(wc * 64 + n * 16 + ln) * 32 + g * 8];
    #pragma unroll
    for (int m = 0; m < 4; ++m)
      #pragma unroll
      for (int n = 0; n < 4; ++n)
        acc[m][n] = MFMA_BF16(af[m], bfr[n], acc[m][n]);
    __syncthreads();
  }

  #pragma unroll
  for (int m = 0; m < 4; ++m) {
    const int rowb = mBase + wr * 64 + m * 16 + g * 4;
    #pragma unroll
    for (int n = 0; n < 4; ++n) {
      const int col = nBase + wc * 64 + n * 16 + ln;
      const float bv = bias[col];
      #pragma unroll
      for (int r = 0; r < 4; ++r) {
        const float vv = acc[m][n][r] + bv;
        const int row = rowb + r;
        if (EPI == 0) {
          const int part = col >> 10;          // 0=q,1=k,2=v
          const int c = col & 1023;
          const int hh = c >> 6, d = c & 63;
          const int bb = row >> 10, s = row & 1023;
          const int bh = bb * NHEADS + hh;
          const unsigned short hv = f2bf(vv);
          if (part == 0)      qb[(bh * SLEN + s) * DHEAD + d] = hv;
          else if (part == 1) kb[(bh * SLEN + s) * DHEAD + d] = hv;
          else                vb[(bh * DHEAD + d) * SLEN + s] = hv;  // V^T
        } else {
          outf[row * N + col] = vv;
        }
      }
    }
  }
}

// ---------------- flash attention ----------------
// grid: 64 (b,h) x 16 q-chunks of 64 rows; block 256 thr = 4 waves x 16 q-rows.
__global__ __launch_bounds__(256) void attn(
    const unsigned short* __restrict__ qb, const unsigned short* __restrict__ kb,
    const unsigned short* __restrict__ vb, const int* __restrict__ Lp,
    unsigned short* __restrict__ yb) {
  const int blk = blockIdx.x;
  const int bh = blk >> 4, qc = blk & 15;
  const int b = bh >> 4, h = bh & 15;
  const int L = Lp[b];
  const int tid = threadIdx.x, w = tid >> 6, l = tid & 63;
  const int g = l >> 4, ln = l & 15;
  const int q0 = qc * 64 + w * 16;

  const unsigned short* qp = qb + (bh * SLEN + q0) * DHEAD;
  const bf16x8 qf0 = *(const bf16x8*)&qp[ln * DHEAD + g * 8];
  const bf16x8 qf1 = *(const bf16x8*)&qp[ln * DHEAD + 32 + g * 8];

  f32x4 zz = {0.f, 0.f, 0.f, 0.f};
  f32x4 o[4] = {zz, zz, zz, zz};
  float mrow[4] = {-__builtin_inff(), -__builtin_inff(), -__builtin_inff(), -__builtin_inff()};
  float lrow[4] = {0.f, 0.f, 0.f, 0.f};

  __shared__ __align__(16) unsigned short pls[4][16 * 40];  // padded stride 40
  unsigned short* pw = pls[w];

  const unsigned short* kp = kb + bh * SLEN * DHEAD;
  const unsigned short* vp = vb + bh * DHEAD * SLEN;

  for (int t = 0; t < SLEN / 32; ++t) {
    const int kb0 = t * 32;
    f32x4 e0 = zz, e1 = zz;
    const unsigned short* k0p = kp + (kb0 + ln) * DHEAD;
    const unsigned short* k1p = k0p + 16 * DHEAD;
    {
      bf16x8 kf;
      kf = *(const bf16x8*)&k0p[g * 8];      e0 = MFMA_BF16(qf0, kf, e0);
      kf = *(const bf16x8*)&k0p[32 + g * 8]; e0 = MFMA_BF16(qf1, kf, e0);
      kf = *(const bf16x8*)&k1p[g * 8];      e1 = MFMA_BF16(qf0, kf, e1);
      kf = *(const bf16x8*)&k1p[32 + g * 8]; e1 = MFMA_BF16(qf1, kf, e1);
    }
    float al[4], p0[4], p1[4];
    #pragma unroll
    for (int r = 0; r < 4; ++r) {
      const int q = q0 + g * 4 + r;
      const int ki0 = kb0 + ln, ki1 = ki0 + 16;
      float s0 = e0[r] * 0.125f;
      float s1 = e1[r] * 0.125f;
      if ((ki0 <= q) && (q < L) && (ki0 < L)) s0 = -1e30f;
      if ((ki1 <= q) && (q < L) && (ki1 < L)) s1 = -1e30f;
      float mx = fmaxf(s0, s1);
      mx = fmaxf(mx, __shfl_xor(mx, 1));
      mx = fmaxf(mx, __shfl_xor(mx, 2));
      mx = fmaxf(mx, __shfl_xor(mx, 4));
      mx = fmaxf(mx, __shfl_xor(mx, 8));
      const float mn = fmaxf(mrow[r], mx);
      const float a = __expf(mrow[r] - mn);
      const float pp0 = __expf(s0 - mn);
      const float pp1 = __expf(s1 - mn);
      float sm = pp0 + pp1;
      sm += __shfl_xor(sm, 1);
      sm += __shfl_xor(sm, 2);
      sm += __shfl_xor(sm, 4);
      sm += __shfl_xor(sm, 8);
      lrow[r] = lrow[r] * a + sm;
      mrow[r] = mn; al[r] = a; p0[r] = pp0; p1[r] = pp1;
    }
    #pragma unroll
    for (int nn = 0; nn < 4; ++nn) {
      o[nn][0] *= al[0]; o[nn][1] *= al[1];
      o[nn][2] *= al[2]; o[nn][3] *= al[3];
    }
    // P (16x32, C-layout) -> LDS row-major (stride 40) -> A-frag
    #pragma unroll
    for (int r = 0; r < 4; ++r) {
      pw[(g * 4 + r) * 40 + ln]      = f2bf(p0[r]);
      pw[(g * 4 + r) * 40 + 16 + ln] = f2bf(p1[r]);
    }
    __syncthreads();   // correctness-first ordering (wave-local in principle)
    const bf16x8 pf = *(const bf16x8*)&pw[ln * 40 + g * 8];
    #pragma unroll
    for (int nt = 0; nt < 4; ++nt) {
      const bf16x8 vf = *(const bf16x8*)&vp[(nt * 16 + ln) * SLEN + kb0 + g * 8];
      o[nt] = MFMA_BF16(pf, vf, o[nt]);
    }
  }

  float inv[4];
  #pragma unroll
  for (int r = 0; r < 4; ++r) inv[r] = 1.0f / lrow[r];
  #pragma unroll
  for (int nt = 0; nt < 4; ++nt)
    #pragma unroll
    for (int r = 0; r < 4; ++r) {
      const int q = q0 + g * 4 + r;
      yb[(b * SLEN + q) * EDIM + h * DHEAD + nt * 16 + ln] = f2bf(o[nt][r] * inv[r]);
    }
}

// ---------------- launch ----------------
extern "C" void kernel_launch(void* const* d_in, const int* in_sizes, int n_in,
                              void* d_out, int out_size, void* d_ws, size_t ws_size,
                              hipStream_t stream) {
  const float* x    = (const float*)d_in[0];
  const int*   mask = (const int*)d_in[1];
  const float* wqkv = (const float*)d_in[2];
  const float* bqkv = (const float*)d_in[3];
  const float* wout = (const float*)d_in[4];
  const float* bout = (const float*)d_in[5];
  float* out = (float*)d_out;

  char* ws = (char*)d_ws;
  const size_t SZ_X   = (size_t)BATCH * SLEN * EDIM * 2;   // 8MB
  const size_t SZ_WQ  = (size_t)3 * EDIM * EDIM * 2;       // 6MB
  const size_t SZ_WO  = (size_t)EDIM * EDIM * 2;           // 2MB
  const size_t SZ_QKV = (size_t)BATCH * NHEADS * SLEN * DHEAD * 2;  // 8MB each

  unsigned short* xb   = (unsigned short*)ws;               ws += SZ_X;
  unsigned short* wqb  = (unsigned short*)ws;               ws += SZ_WQ;
  unsigned short* wob  = (unsigned short*)ws;               ws += SZ_WO;
  unsigned short* qbuf = (unsigned short*)ws;               ws += SZ_QKV;
  unsigned short* kbuf = (unsigned short*)ws;               ws += SZ_QKV;
  unsigned short* vbuf = (unsigned short*)ws;               ws += SZ_QKV;
  unsigned short* ybuf = (unsigned short*)ws;               ws += SZ_X;
  int* Lbuf = (int*)ws;

  prep_cast<<<8192, 256, 0, stream>>>(x, wqkv, wout, xb, wqb, wob);
  mask_sum<<<BATCH, 256, 0, stream>>>(mask, Lbuf);
  gemm_bt<0><<<(4096 / 128) * (3072 / 128), 256, 0, stream>>>(
      xb, wqb, 4096, 3072, 1024, bqkv, nullptr, qbuf, kbuf, vbuf);
  attn<<<BATCH * NHEADS * (SLEN / 64), 256, 0, stream>>>(qbuf, kbuf, vbuf, Lbuf, ybuf);
  gemm_bt<1><<<(4096 / 128) * (1024 / 128), 256, 0, stream>>>(
      ybuf, wob, 4096, 1024, 1024, bout, out, nullptr, nullptr, nullptr);
}

// Round 4
// 241.133 us; speedup vs baseline: 1.1664x; 1.1664x over previous
//
#include <hip/hip_runtime.h>

// Fused MHA: x(4,1024,1024) fp32, mask(4,1024) i32, w_qkv(3072,1024), b_qkv,
// w_out(1024,1024), b_out -> out(4,1024,1024) fp32.
// Pipeline: prep-cast -> mask-sum -> qkv GEMM (bf16 MFMA) -> flash attn -> out GEMM.
// R3 (resubmit; container infra failure): attn = swapped-operand 32x32 MFMA flash,
// in-register softmax; all cross-lane ops via proven __shfl_xor / f2bf primitives.

#define NHEADS 16
#define DHEAD  64
#define EDIM   1024
#define SLEN   1024
#define BATCH  4

typedef short bf16x8 __attribute__((ext_vector_type(8)));
typedef float f32x4  __attribute__((ext_vector_type(4)));
typedef float f32x16 __attribute__((ext_vector_type(16)));

#define MFMA_BF16(a,b,c) __builtin_amdgcn_mfma_f32_16x16x32_bf16((a),(b),(c),0,0,0)
#define MFMA32(a,b,c)    __builtin_amdgcn_mfma_f32_32x32x16_bf16((a),(b),(c),0,0,0)

typedef const __attribute__((address_space(1))) void gvoid_t;
typedef __attribute__((address_space(3))) void lvoid_t;

__device__ __forceinline__ unsigned short f2bf(float x) {
  union { float f; unsigned int u; } v; v.f = x;
  unsigned int r = v.u + 0x7fffu + ((v.u >> 16) & 1u);
  return (unsigned short)(r >> 16);
}

__device__ __forceinline__ unsigned pack2(float lo, float hi) {
  return (unsigned)f2bf(lo) | ((unsigned)f2bf(hi) << 16);
}

__device__ __forceinline__ void gl2lds16(const void* g, void* l) {
  __builtin_amdgcn_global_load_lds((gvoid_t*)g, (lvoid_t*)l, 16, 0, 0);
}

// ---------------- prep: fp32 -> bf16 casts ----------------
__global__ __launch_bounds__(256) void prep_cast(
    const float* __restrict__ x, const float* __restrict__ wq,
    const float* __restrict__ wo,
    unsigned short* __restrict__ xb, unsigned short* __restrict__ wqb,
    unsigned short* __restrict__ wob) {
  int i = blockIdx.x * 256 + threadIdx.x;
  const int NX  = BATCH * SLEN * EDIM / 4;   // 1048576
  const int NW1 = 3 * EDIM * EDIM / 4;       // 786432
  const float4* src; unsigned short* dst; int j;
  if (i < NX)           { src = (const float4*)x;  dst = xb;  j = i; }
  else if (i < NX+NW1)  { src = (const float4*)wq; dst = wqb; j = i - NX; }
  else                  { src = (const float4*)wo; dst = wob; j = i - NX - NW1; }
  float4 v = src[j];
  ushort4 o;
  o.x = f2bf(v.x); o.y = f2bf(v.y); o.z = f2bf(v.z); o.w = f2bf(v.w);
  ((ushort4*)dst)[j] = o;
}

// ---------------- mask row-sum: L[b] ----------------
__global__ __launch_bounds__(256) void mask_sum(const int* __restrict__ mask,
                                                int* __restrict__ L) {
  int b = blockIdx.x;
  int t = threadIdx.x;
  int s = 0;
  for (int i = t; i < SLEN; i += 256) s += mask[b * SLEN + i];
  #pragma unroll
  for (int m = 1; m < 64; m <<= 1) s += __shfl_xor(s, m);
  __shared__ int part[4];
  if ((t & 63) == 0) part[t >> 6] = s;
  __syncthreads();
  if (t == 0) L[b] = part[0] + part[1] + part[2] + part[3];
}

// ---------------- GEMM C = A @ B^T (A:[M][K], B:[N][K], bf16, m97 structure) ----
template<int EPI>
__global__ __launch_bounds__(256) void gemm_bt(
    const unsigned short* __restrict__ A, const unsigned short* __restrict__ B,
    int M, int N, int K,
    const float* __restrict__ bias,
    float* __restrict__ outf,
    unsigned short* __restrict__ qb, unsigned short* __restrict__ kb,
    unsigned short* __restrict__ vb) {
  __shared__ __align__(16) unsigned short lds_a[128 * 32];
  __shared__ __align__(16) unsigned short lds_b[128 * 32];
  const int tid = threadIdx.x;
  const int w = tid >> 6, l = tid & 63;
  const int g = l >> 4, ln = l & 15;
  const int ntile = N >> 7;
  const int tm = blockIdx.x / ntile, tn = blockIdx.x % ntile;
  const int mBase = tm << 7, nBase = tn << 7;
  const int wr = w >> 1, wc = w & 1;

  f32x4 zz = {0.f, 0.f, 0.f, 0.f};
  f32x4 acc[4][4];
  #pragma unroll
  for (int m = 0; m < 4; ++m)
    #pragma unroll
    for (int n = 0; n < 4; ++n) acc[m][n] = zz;

  const int u0 = tid, u1 = tid + 256;
  const int r0 = u0 >> 2, c0 = (u0 & 3) << 3;
  const int r1 = u1 >> 2, c1 = (u1 & 3) << 3;
  const unsigned short* Ab = A + mBase * K;
  const unsigned short* Bb = B + nBase * K;
  unsigned short* da0 = &lds_a[(w * 64) * 8];
  unsigned short* da1 = &lds_a[(256 + w * 64) * 8];
  unsigned short* db0 = &lds_b[(w * 64) * 8];
  unsigned short* db1 = &lds_b[(256 + w * 64) * 8];

  for (int k0 = 0; k0 < K; k0 += 32) {
    gl2lds16(Ab + r0 * K + k0 + c0, da0);
    gl2lds16(Ab + r1 * K + k0 + c1, da1);
    gl2lds16(Bb + r0 * K + k0 + c0, db0);
    gl2lds16(Bb + r1 * K + k0 + c1, db1);
    __syncthreads();
    bf16x8 af[4], bfr[4];
    #pragma unroll
    for (int m = 0; m < 4; ++m)
      af[m] = *(const bf16x8*)&lds_a[(wr * 64 + m * 16 + ln) * 32 + g * 8];
    #pragma unroll
    for (int n = 0; n < 4; ++n)
      bfr[n] = *(const bf16x8*)&lds_b[(wc * 64 + n * 16 + ln) * 32 + g * 8];
    #pragma unroll
    for (int m = 0; m < 4; ++m)
      #pragma unroll
      for (int n = 0; n < 4; ++n)
        acc[m][n] = MFMA_BF16(af[m], bfr[n], acc[m][n]);
    __syncthreads();
  }

  #pragma unroll
  for (int m = 0; m < 4; ++m) {
    const int rowb = mBase + wr * 64 + m * 16 + g * 4;
    #pragma unroll
    for (int n = 0; n < 4; ++n) {
      const int col = nBase + wc * 64 + n * 16 + ln;
      const float bv = bias[col];
      #pragma unroll
      for (int r = 0; r < 4; ++r) {
        const float vv = acc[m][n][r] + bv;
        const int row = rowb + r;
        if (EPI == 0) {
          const int part = col >> 10;          // 0=q,1=k,2=v
          const int c = col & 1023;
          const int hh = c >> 6, d = c & 63;
          const int bb = row >> 10, s = row & 1023;
          const int bh = bb * NHEADS + hh;
          const unsigned short hv = f2bf(vv);
          if (part == 0)      qb[(bh * SLEN + s) * DHEAD + d] = hv;
          else if (part == 1) kb[(bh * SLEN + s) * DHEAD + d] = hv;
          else                vb[(bh * DHEAD + d) * SLEN + s] = hv;  // V^T
        } else {
          outf[row * N + col] = vv;
        }
      }
    }
  }
}

// ---------------- flash attention (swapped-operand 32x32, no LDS/barriers) ----
// 1-wave blocks (64 thr). Each wave: 32 q-rows, iterate 32-key tiles.
// S^T = mfma(K, Q): lane holds q=lane&31, keys crow(r,hi)=(r&3)+8*(r>>2)+4*hi.
// O^T = mfma(V^T, P): lane holds q=lane&31, d=crow(r,hi) (+32 for o1).
__global__ __launch_bounds__(64) void attn(
    const unsigned short* __restrict__ qb, const unsigned short* __restrict__ kb,
    const unsigned short* __restrict__ vb, const int* __restrict__ Lp,
    unsigned short* __restrict__ yb) {
  const int bid = blockIdx.x;
  const int lid = (bid & 7) * 256 + (bid >> 3);   // XCD-chunked swizzle (2048%8==0)
  const int bh = lid >> 5, qw = lid & 31;
  const int b = bh >> 4, h = bh & 15;
  const int L = Lp[b];
  const int l = threadIdx.x;
  const int l31 = l & 31, hi = l >> 5;
  const int q = qw * 32 + l31;

  const unsigned short* qp = qb + (size_t)bh * SLEN * DHEAD;
  const unsigned short* kp = kb + (size_t)bh * SLEN * DHEAD;
  const unsigned short* vp = vb + (size_t)bh * DHEAD * SLEN;

  // Q B-frags: B[k=dh][col=q], lane: Q[q][c*16 + hi*8 + j]
  bf16x8 qf[4];
  #pragma unroll
  for (int c = 0; c < 4; ++c)
    qf[c] = *(const bf16x8*)&qp[q * DHEAD + c * 16 + hi * 8];

  f32x16 o0 = {}; f32x16 o1 = {};
  float mrow = -__builtin_inff(), lrow = 0.f;
  const bool qv = q < L;

  for (int t = 0; t < SLEN / 32; ++t) {
    const int kb0 = t * 32;
    // --- QK^T (swapped): A = K rows (key=lane&31), B = Q ---
    f32x16 e = {};
    __builtin_amdgcn_s_setprio(1);
    #pragma unroll
    for (int c = 0; c < 4; ++c) {
      const bf16x8 kf = *(const bf16x8*)&kp[(kb0 + l31) * DHEAD + c * 16 + hi * 8];
      e = MFMA32(kf, qf[c], e);
    }
    __builtin_amdgcn_s_setprio(0);

    // --- mask + scale + online softmax (lane-local + one cross-half shfl) ---
    float pm = -__builtin_inff();
    #pragma unroll
    for (int r = 0; r < 16; ++r) {
      const int key = kb0 + (r & 3) + 8 * (r >> 2) + 4 * hi;
      float s = e[r] * 0.125f;
      if (qv && (key <= q) && (key < L)) s = -1e30f;
      e[r] = s;
      pm = fmaxf(pm, s);
    }
    pm = fmaxf(pm, __shfl_xor(pm, 32));
    const float mn = fmaxf(mrow, pm);
    const float a = __expf(mrow - mn);
    float sum = 0.f;
    #pragma unroll
    for (int r = 0; r < 16; ++r) { const float pe = __expf(e[r] - mn); e[r] = pe; sum += pe; }
    sum += __shfl_xor(sum, 32);
    lrow = lrow * a + sum;
    mrow = mn;
    #pragma unroll
    for (int r = 0; r < 16; ++r) { o0[r] *= a; o1[r] *= a; }

    // --- P -> bf16 B-frags: pack pairs (f2bf) + cross-half exchange (shfl) ---
    // B-frag word j at lane(hi) must hold keys kc*16 + 8*hi + 2j, +1.
    bf16x8 pbf[2];
    #pragma unroll
    for (int kc = 0; kc < 2; ++kc) {
      const unsigned wA = pack2(e[8*kc+0], e[8*kc+1]);   // own keys  0,1 (+4hi)
      const unsigned wB = pack2(e[8*kc+2], e[8*kc+3]);   // own keys  2,3 (+4hi)
      const unsigned wC = pack2(e[8*kc+4], e[8*kc+5]);   // own keys  8,9 (+4hi)
      const unsigned wD = pack2(e[8*kc+6], e[8*kc+7]);   // own keys 10,11 (+4hi)
      const unsigned pA = __shfl_xor(wA, 32);
      const unsigned pB = __shfl_xor(wB, 32);
      const unsigned pC = __shfl_xor(wC, 32);
      const unsigned pD = __shfl_xor(wD, 32);
      union { unsigned u[4]; bf16x8 v; } pk;
      pk.u[0] = hi ? pC : wA;   // keys 8,9   / 0,1
      pk.u[1] = hi ? pD : wB;   // keys 10,11 / 2,3
      pk.u[2] = hi ? wC : pA;   // keys 12,13 / 4,5
      pk.u[3] = hi ? wD : pB;   // keys 14,15 / 6,7
      pbf[kc] = pk.v;
    }

    // --- PV: O^T += V^T * P ---
    __builtin_amdgcn_s_setprio(1);
    #pragma unroll
    for (int kc = 0; kc < 2; ++kc) {
      const bf16x8 vf0 = *(const bf16x8*)&vp[l31 * SLEN + kb0 + kc * 16 + hi * 8];
      const bf16x8 vf1 = *(const bf16x8*)&vp[(32 + l31) * SLEN + kb0 + kc * 16 + hi * 8];
      o0 = MFMA32(vf0, pbf[kc], o0);
      o1 = MFMA32(vf1, pbf[kc], o1);
    }
    __builtin_amdgcn_s_setprio(0);
  }

  const float inv = 1.0f / lrow;
  unsigned short* yrow = yb + (size_t)(b * SLEN + q) * EDIM + h * DHEAD;
  #pragma unroll
  for (int rq = 0; rq < 4; ++rq) {
    ushort4 s0, s1;
    s0.x = f2bf(o0[4*rq+0] * inv); s0.y = f2bf(o0[4*rq+1] * inv);
    s0.z = f2bf(o0[4*rq+2] * inv); s0.w = f2bf(o0[4*rq+3] * inv);
    s1.x = f2bf(o1[4*rq+0] * inv); s1.y = f2bf(o1[4*rq+1] * inv);
    s1.z = f2bf(o1[4*rq+2] * inv); s1.w = f2bf(o1[4*rq+3] * inv);
    *(ushort4*)&yrow[8*rq + 4*hi]      = s0;   // d = 8*rq + 4*hi + 0..3
    *(ushort4*)&yrow[32 + 8*rq + 4*hi] = s1;   // d+32
  }
}

// ---------------- launch ----------------
extern "C" void kernel_launch(void* const* d_in, const int* in_sizes, int n_in,
                              void* d_out, int out_size, void* d_ws, size_t ws_size,
                              hipStream_t stream) {
  const float* x    = (const float*)d_in[0];
  const int*   mask = (const int*)d_in[1];
  const float* wqkv = (const float*)d_in[2];
  const float* bqkv = (const float*)d_in[3];
  const float* wout = (const float*)d_in[4];
  const float* bout = (const float*)d_in[5];
  float* out = (float*)d_out;

  char* ws = (char*)d_ws;
  const size_t SZ_X   = (size_t)BATCH * SLEN * EDIM * 2;   // 8MB
  const size_t SZ_WQ  = (size_t)3 * EDIM * EDIM * 2;       // 6MB
  const size_t SZ_WO  = (size_t)EDIM * EDIM * 2;           // 2MB
  const size_t SZ_QKV = (size_t)BATCH * NHEADS * SLEN * DHEAD * 2;  // 8MB each

  unsigned short* xb   = (unsigned short*)ws;               ws += SZ_X;
  unsigned short* wqb  = (unsigned short*)ws;               ws += SZ_WQ;
  unsigned short* wob  = (unsigned short*)ws;               ws += SZ_WO;
  unsigned short* qbuf = (unsigned short*)ws;               ws += SZ_QKV;
  unsigned short* kbuf = (unsigned short*)ws;               ws += SZ_QKV;
  unsigned short* vbuf = (unsigned short*)ws;               ws += SZ_QKV;
  unsigned short* ybuf = (unsigned short*)ws;               ws += SZ_X;
  int* Lbuf = (int*)ws;

  prep_cast<<<8192, 256, 0, stream>>>(x, wqkv, wout, xb, wqb, wob);
  mask_sum<<<BATCH, 256, 0, stream>>>(mask, Lbuf);
  gemm_bt<0><<<(4096 / 128) * (3072 / 128), 256, 0, stream>>>(
      xb, wqb, 4096, 3072, 1024, bqkv, nullptr, qbuf, kbuf, vbuf);
  attn<<<BATCH * NHEADS * (SLEN / 32), 64, 0, stream>>>(qbuf, kbuf, vbuf, Lbuf, ybuf);
  gemm_bt<1><<<(4096 / 128) * (1024 / 128), 256, 0, stream>>>(
      ybuf, wob, 4096, 1024, 1024, bout, out, nullptr, nullptr, nullptr);
}